// Round 1
// baseline (440.630 us; speedup 1.0000x reference)
//
#include <hip/hip_runtime.h>
#include <hip/hip_bf16.h>
#include <cstdint>
#include <cstddef>

#define B_ 8
#define C_ 256
#define N_ 2048
#define H_ 32

// ---------------- K1: q,k projections (q,k stored [B,H,N]) ----------------
__global__ __launch_bounds__(256) void qk_kernel(
    const float* __restrict__ x, const float* __restrict__ wq,
    const float* __restrict__ bq, const float* __restrict__ wk,
    const float* __restrict__ bk, float* __restrict__ q, float* __restrict__ kk) {
  int n = blockIdx.x * 64 + (threadIdx.x & 63);
  // h is wave-uniform by construction; force scalarization of weight loads
  int h = __builtin_amdgcn_readfirstlane(blockIdx.y * 4 + (threadIdx.x >> 6));
  int b = blockIdx.z;
  const float* xb = x + (size_t)b * C_ * N_ + n;
  const float* wqh = wq + h * C_;
  const float* wkh = wk + h * C_;
  float aq = bq[h], ak = bk[h];
#pragma unroll 8
  for (int c = 0; c < C_; ++c) {
    float xv = xb[(size_t)c * N_];     // coalesced across lanes (n)
    aq = fmaf(xv, wqh[c], aq);
    ak = fmaf(xv, wkh[c], ak);
  }
  q[((size_t)b * H_ + h) * N_ + n] = aq;
  kk[((size_t)b * H_ + h) * N_ + n] = ak;
}

// ---------------- shared GEMM skeleton ----------------
// C[m][n'] = sum_k A[k][m] * B[n'][k]  (+ bias[n'] | + residual[m][n'])
// MODE 0: B is fp32, epilogue adds aux[n'] (bias)        -> used for v = x^T * wv^T
// MODE 1: B is bf16, epilogue adds aux[m*ldc+n] (resid)  -> used for out = v_t^T * W^T + x
#define BM 64
#define BN 128
#define BK 32

template <int MODE>
__global__ __launch_bounds__(256) void gemm_kernel(
    const float* __restrict__ A, const void* __restrict__ Bvp,
    float* __restrict__ Co, const float* __restrict__ aux,
    int K, int lda, int ldb, int ldc,
    size_t batchA, size_t batchB, size_t batchC, int nBase) {
  __shared__ float As[BK][BM];        // stride 64: 2-way bank alias (free)
  __shared__ float Bs[BK][BN + 4];    // row stride 132 floats (16B-aligned rows)
  int tid = threadIdx.x;
  int m0 = blockIdx.x * BM;
  int n0 = blockIdx.y * BN;
  int z  = blockIdx.z;
  A  += batchA * z;
  Co += batchC * z;
  const float* auxp = aux;
  if (MODE == 1) auxp += batchC * z;
  int am = tid & 63, akr = tid >> 6;   // A staging: lanes over m
  int bkr = tid & 31, bnr = tid >> 5;  // B staging: lanes over k
  int tm = (tid & 15) * 4;             // thread micro-tile: 4 m x 8 n'
  int tn = (tid >> 4) * 8;
  float acc[4][8] = {};
  for (int k0 = 0; k0 < K; k0 += BK) {
    __syncthreads();
#pragma unroll
    for (int p = 0; p < 8; ++p) {
      int kq = akr + p * 4;
      As[kq][am] = A[(size_t)(k0 + kq) * lda + m0 + am];
    }
    if (MODE == 0) {
      const float* Bp = (const float*)Bvp;
#pragma unroll
      for (int p = 0; p < 16; ++p) {
        int nn = bnr + p * 8;
        Bs[bkr][nn] = Bp[batchB * z + (size_t)(n0 + nn) * ldb + k0 + bkr];
      }
    } else {
      const __hip_bfloat16* Bp = (const __hip_bfloat16*)Bvp;
#pragma unroll
      for (int p = 0; p < 16; ++p) {
        int nn = bnr + p * 8;
        Bs[bkr][nn] = __bfloat162float(Bp[batchB * z + (size_t)(n0 + nn) * ldb + k0 + bkr]);
      }
    }
    __syncthreads();
#pragma unroll
    for (int kq = 0; kq < BK; ++kq) {
      float4 a  = *(const float4*)&As[kq][tm];
      float4 b0 = *(const float4*)&Bs[kq][tn];
      float4 b1 = *(const float4*)&Bs[kq][tn + 4];
      float av[4] = {a.x, a.y, a.z, a.w};
      float bw[8] = {b0.x, b0.y, b0.z, b0.w, b1.x, b1.y, b1.z, b1.w};
#pragma unroll
      for (int i = 0; i < 4; ++i)
#pragma unroll
        for (int j = 0; j < 8; ++j)
          acc[i][j] = fmaf(av[i], bw[j], acc[i][j]);
    }
  }
#pragma unroll
  for (int i = 0; i < 4; ++i) {
    int m = m0 + tm + i;
#pragma unroll
    for (int j = 0; j < 8; ++j) {
      int n = nBase + n0 + tn + j;
      float v = acc[i][j];
      if (MODE == 0) v += auxp[n];
      else           v += auxp[(size_t)m * ldc + n];
      Co[(size_t)m * ldc + n] = v;
    }
  }
}

// ---------------- K3: energy (QK^T) + softmax -> W (bf16) ----------------
#define TI 4
__global__ __launch_bounds__(256) void softmax_kernel(
    const float* __restrict__ q, const float* __restrict__ kmat,
    __hip_bfloat16* __restrict__ W, int iBase, int chunkN) {
  __shared__ float e[TI][N_];     // 32 KB
  __shared__ float qt[TI][H_];
  __shared__ float red[4][TI];
  int tid = threadIdx.x;
  int b = blockIdx.y;
  int iT = blockIdx.x * TI;       // chunk-local row base
  int iG = iBase + iT;            // global query index
  if (tid < TI * H_) {
    int i = tid >> 5, h = tid & 31;
    qt[i][h] = q[((size_t)b * H_ + h) * N_ + iG + i];
  }
  __syncthreads();
  float mloc[TI];
#pragma unroll
  for (int i = 0; i < TI; ++i) mloc[i] = -3.0e38f;
#pragma unroll 1
  for (int s = 0; s < 8; ++s) {
    int j = tid + s * 256;
    float kj[32];
#pragma unroll
    for (int h = 0; h < 32; ++h) kj[h] = kmat[((size_t)b * H_ + h) * N_ + j];
#pragma unroll
    for (int i = 0; i < TI; ++i) {
      float acc = 0.f;
#pragma unroll
      for (int h4 = 0; h4 < 8; ++h4) {
        float4 qv = *(const float4*)&qt[i][h4 * 4];
        acc = fmaf(qv.x, kj[h4 * 4 + 0], acc);
        acc = fmaf(qv.y, kj[h4 * 4 + 1], acc);
        acc = fmaf(qv.z, kj[h4 * 4 + 2], acc);
        acc = fmaf(qv.w, kj[h4 * 4 + 3], acc);
      }
      e[i][j] = acc;
      mloc[i] = fmaxf(mloc[i], acc);
    }
  }
  int wave = tid >> 6, lane = tid & 63;
#pragma unroll
  for (int i = 0; i < TI; ++i)
#pragma unroll
    for (int off = 32; off > 0; off >>= 1)
      mloc[i] = fmaxf(mloc[i], __shfl_xor(mloc[i], off));
  if (lane == 0) {
#pragma unroll
    for (int i = 0; i < TI; ++i) red[wave][i] = mloc[i];
  }
  __syncthreads();
  float mfin[TI];
#pragma unroll
  for (int i = 0; i < TI; ++i)
    mfin[i] = fmaxf(fmaxf(red[0][i], red[1][i]), fmaxf(red[2][i], red[3][i]));
  __syncthreads();   // everyone done reading red before it is reused
  float lloc[TI] = {};
#pragma unroll 1
  for (int s = 0; s < 8; ++s) {
    int j = tid + s * 256;
#pragma unroll
    for (int i = 0; i < TI; ++i) {
      float v = __expf(e[i][j] - mfin[i]);
      e[i][j] = v;
      lloc[i] += v;
    }
  }
#pragma unroll
  for (int i = 0; i < TI; ++i)
#pragma unroll
    for (int off = 32; off > 0; off >>= 1)
      lloc[i] += __shfl_xor(lloc[i], off);
  if (lane == 0) {
#pragma unroll
    for (int i = 0; i < TI; ++i) red[wave][i] = lloc[i];
  }
  __syncthreads();
  float linv[TI];
#pragma unroll
  for (int i = 0; i < TI; ++i)
    linv[i] = 1.0f / (red[0][i] + red[1][i] + red[2][i] + red[3][i]);
#pragma unroll 1
  for (int s = 0; s < 8; ++s) {
    int j = tid + s * 256;
#pragma unroll
    for (int i = 0; i < TI; ++i)
      W[((size_t)b * chunkN + iT + i) * (size_t)N_ + j] =
          __float2bfloat16(e[i][j] * linv[i]);
  }
}

extern "C" void kernel_launch(void* const* d_in, const int* in_sizes, int n_in,
                              void* d_out, int out_size, void* d_ws, size_t ws_size,
                              hipStream_t stream) {
  const float* x  = (const float*)d_in[0];
  const float* wq = (const float*)d_in[1];
  const float* bq = (const float*)d_in[2];
  const float* wk = (const float*)d_in[3];
  const float* bk = (const float*)d_in[4];
  const float* wv = (const float*)d_in[5];
  const float* bv = (const float*)d_in[6];
  float* out = (float*)d_out;

  float* ws = (float*)d_ws;
  float* q  = ws;                                    // B*H*N fp32 (2 MB)
  float* kk = ws + (size_t)B_ * H_ * N_;             // B*H*N fp32 (2 MB)
  float* vt = ws + 2 * (size_t)B_ * H_ * N_;         // B*N*C fp32, [b][n][d] (16 MB)
  __hip_bfloat16* W = (__hip_bfloat16*)(vt + (size_t)B_ * N_ * C_);

  size_t baseBytes = ((size_t)2 * B_ * H_ * N_ + (size_t)B_ * N_ * C_) * 4;
  // Full softmax-weight matrix needs 67 MB (bf16). If workspace is smaller,
  // fall back to i-chunks of 256 (8.4 MB per chunk). ws_size is constant
  // across calls, so this branch is graph-capture safe.
  int chunk = (ws_size >= baseBytes + (size_t)B_ * N_ * N_ * 2) ? N_ : 256;

  // K1: q,k
  qk_kernel<<<dim3(N_ / 64, H_ / 4, B_), 256, 0, stream>>>(x, wq, bq, wk, bk, q, kk);

  // K2: v_t[b][n][d] = sum_c x[b][c][n]*wv[d][c] + bv[d]
  // GEMM: A = x[b] ([K=c][M=n], lda=N), B = wv ([N'=d][K=c], ldb=C)
  gemm_kernel<0><<<dim3(N_ / BM, C_ / BN, B_), 256, 0, stream>>>(
      x, (const void*)wv, vt, bv,
      /*K=*/C_, /*lda=*/N_, /*ldb=*/C_, /*ldc=*/C_,
      /*batchA=*/(size_t)C_ * N_, /*batchB=*/0, /*batchC=*/(size_t)N_ * C_, 0);

  for (int cc = 0; cc < N_ / chunk; ++cc) {
    // K3: W[b][i][j] = softmax_j( q[b,:,i] . k[b,:,j] )  (bf16)
    softmax_kernel<<<dim3(chunk / TI, B_), 256, 0, stream>>>(q, kk, W, cc * chunk, chunk);
    // K4: out[b][c][i] = sum_j v_t[b][j][c] * W[b][i][j] + x[b][c][i]
    // GEMM: A = v_t[b] ([K=j][M=c], lda=C), B = W[b] ([N'=i][K=j], ldb=N)
    gemm_kernel<1><<<dim3(C_ / BM, chunk / BN, B_), 256, 0, stream>>>(
        vt, (const void*)W, out, x,
        /*K=*/N_, /*lda=*/C_, /*ldb=*/N_, /*ldc=*/N_,
        /*batchA=*/(size_t)N_ * C_, /*batchB=*/(size_t)chunk * N_,
        /*batchC=*/(size_t)C_ * N_, /*nBase=*/cc * chunk);
  }
}

// Round 2
// 245.352 us; speedup vs baseline: 1.7959x; 1.7959x over previous
//
#include <hip/hip_runtime.h>
#include <hip/hip_bf16.h>
#include <cstdint>
#include <cstddef>

#define B_ 8
#define C_ 256
#define N_ 2048
#define H_ 32

typedef __bf16 bf8 __attribute__((ext_vector_type(8)));
typedef float f4 __attribute__((ext_vector_type(4)));

__device__ inline void gload_lds16(const void* g, void* l) {
  __builtin_amdgcn_global_load_lds(
      (const __attribute__((address_space(1))) unsigned int*)g,
      (__attribute__((address_space(3))) unsigned int*)l, 16, 0, 0);
}

// ---------------- K1: q,k projections (q,k stored [B,H,N]) ----------------
__global__ __launch_bounds__(256) void qk_kernel(
    const float* __restrict__ x, const float* __restrict__ wq,
    const float* __restrict__ bq, const float* __restrict__ wk,
    const float* __restrict__ bk, float* __restrict__ q, float* __restrict__ kk) {
  int n = blockIdx.x * 64 + (threadIdx.x & 63);
  int h = __builtin_amdgcn_readfirstlane(blockIdx.y * 4 + (threadIdx.x >> 6));
  int b = blockIdx.z;
  const float* xb = x + (size_t)b * C_ * N_ + n;
  const float* wqh = wq + h * C_;
  const float* wkh = wk + h * C_;
  float aq = bq[h], ak = bk[h];
#pragma unroll 8
  for (int c = 0; c < C_; ++c) {
    float xv = xb[(size_t)c * N_];
    aq = fmaf(xv, wqh[c], aq);
    ak = fmaf(xv, wkh[c], ak);
  }
  q[((size_t)b * H_ + h) * N_ + n] = aq;
  kk[((size_t)b * H_ + h) * N_ + n] = ak;
}

// ---------------- transpose+cast: x[b][c][n] fp32 -> xt[b][n][c] bf16 ------
__global__ __launch_bounds__(256) void transpose_kernel(
    const float* __restrict__ x, __hip_bfloat16* __restrict__ xt) {
  __shared__ __hip_bfloat16 t[64][66];  // row stride 132 B = 33 dwords -> conflict-free columns
  int b = blockIdx.z;
  int n0 = blockIdx.x * 64, c0 = blockIdx.y * 64;
  const float* xb = x + (size_t)b * C_ * N_;
  __hip_bfloat16* xtb = xt + (size_t)b * N_ * C_;
  int tl = threadIdx.x & 63, tq = threadIdx.x >> 6;
#pragma unroll
  for (int p = 0; p < 16; ++p) {
    int c = tq * 16 + p;
    t[c][tl] = __float2bfloat16(xb[(size_t)(c0 + c) * N_ + n0 + tl]);
  }
  __syncthreads();
#pragma unroll
  for (int p = 0; p < 16; ++p) {
    int n = tq * 16 + p;
    xtb[(size_t)(n0 + n) * C_ + c0 + tl] = t[tl][n];
  }
}

// ---------------- tiny: wv fp32 -> bf16 ----------------
__global__ __launch_bounds__(256) void cvt_kernel(const float* __restrict__ s,
                                                  __hip_bfloat16* __restrict__ d, int n) {
  int i = blockIdx.x * 256 + threadIdx.x;
  if (i < n) d[i] = __float2bfloat16(s[i]);
}

// ---------------- MFMA GEMM: C[m][n] = sum_k A[m][k]*B[n][k] ---------------
// A: bf16 [M][lda], B: bf16 [N][ldb] (both k-contiguous).
// MODE 0: Co bf16, += aux[m] (bias).  MODE 1: Co fp32, += aux (residual).
#define TM 128
#define TN 128
#define TKS 32

template <int MODE>
__global__ __launch_bounds__(256) void mfma_gemm(
    const __hip_bfloat16* __restrict__ A, const __hip_bfloat16* __restrict__ Bm,
    void* __restrict__ Co, const float* __restrict__ aux,
    int K, int lda, int ldb, int ldc,
    size_t batchA, size_t batchB, size_t batchC, int nBase) {
  __shared__ __attribute__((aligned(16))) __hip_bfloat16 As[TM * TKS];
  __shared__ __attribute__((aligned(16))) __hip_bfloat16 Bs[TN * TKS];
  int tid = threadIdx.x;
  int wv = tid >> 6, lane = tid & 63;
  int z = blockIdx.z;
  const __hip_bfloat16* Ab = A + batchA * z + (size_t)(blockIdx.x * TM) * lda;
  const __hip_bfloat16* Bb = Bm + batchB * z + (size_t)(blockIdx.y * TN) * ldb;
  int srow = wv * 32 + (lane >> 2);   // staging row (this wave covers srow, srow+16)
  int skcol = (lane & 3) * 8;         // staging k-offset (8 bf16 = 16 B)
  int wm = (wv & 1) * 64, wn = (wv >> 1) * 64;
  int fcol = (lane & 15), fk = (lane >> 4) * 8;
  f4 acc[4][4] = {};
  for (int k0 = 0; k0 < K; k0 += TKS) {
    __syncthreads();
    gload_lds16(Ab + (size_t)srow * lda + k0 + skcol, &As[(wv * 32) * TKS]);
    gload_lds16(Ab + (size_t)(srow + 16) * lda + k0 + skcol, &As[(wv * 32 + 16) * TKS]);
    gload_lds16(Bb + (size_t)srow * ldb + k0 + skcol, &Bs[(wv * 32) * TKS]);
    gload_lds16(Bb + (size_t)(srow + 16) * ldb + k0 + skcol, &Bs[(wv * 32 + 16) * TKS]);
    __syncthreads();
    bf8 af[4], bf[4];
#pragma unroll
    for (int t = 0; t < 4; ++t) {
      af[t] = *(const bf8*)&As[(wm + t * 16 + fcol) * TKS + fk];
      bf[t] = *(const bf8*)&Bs[(wn + t * 16 + fcol) * TKS + fk];
    }
#pragma unroll
    for (int ti = 0; ti < 4; ++ti)
#pragma unroll
      for (int tj = 0; tj < 4; ++tj)
        acc[ti][tj] = __builtin_amdgcn_mfma_f32_16x16x32_bf16(af[ti], bf[tj], acc[ti][tj], 0, 0, 0);
  }
  // epilogue: D row = (lane>>4)*4 + r (M index), col = lane&15 (N index)
  int rq = (lane >> 4) * 4;
#pragma unroll
  for (int ti = 0; ti < 4; ++ti) {
#pragma unroll
    for (int r = 0; r < 4; ++r) {
      int m = blockIdx.x * TM + wm + ti * 16 + rq + r;
#pragma unroll
      for (int tj = 0; tj < 4; ++tj) {
        int n = nBase + blockIdx.y * TN + wn + tj * 16 + fcol;
        float vacc = acc[ti][tj][r];
        if (MODE == 0) {
          ((__hip_bfloat16*)Co)[batchC * z + (size_t)m * ldc + n] =
              __float2bfloat16(vacc + aux[m]);
        } else {
          size_t off = batchC * z + (size_t)m * ldc + n;
          ((float*)Co)[off] = vacc + aux[off];
        }
      }
    }
  }
}

// ---------------- K3: energy (QK^T) + softmax -> W (bf16) ----------------
#define TI 4
__global__ __launch_bounds__(256) void softmax_kernel(
    const float* __restrict__ q, const float* __restrict__ kmat,
    __hip_bfloat16* __restrict__ W, int iBase, int chunkN) {
  __shared__ float e[TI][N_];
  __shared__ float qt[TI][H_];
  __shared__ float red[4][TI];
  int tid = threadIdx.x;
  int b = blockIdx.y;
  int iT = blockIdx.x * TI;
  int iG = iBase + iT;
  if (tid < TI * H_) {
    int i = tid >> 5, h = tid & 31;
    qt[i][h] = q[((size_t)b * H_ + h) * N_ + iG + i];
  }
  __syncthreads();
  float mloc[TI];
#pragma unroll
  for (int i = 0; i < TI; ++i) mloc[i] = -3.0e38f;
#pragma unroll 1
  for (int s = 0; s < 8; ++s) {
    int j = tid + s * 256;
    float kj[32];
#pragma unroll
    for (int h = 0; h < 32; ++h) kj[h] = kmat[((size_t)b * H_ + h) * N_ + j];
#pragma unroll
    for (int i = 0; i < TI; ++i) {
      float acc = 0.f;
#pragma unroll
      for (int h4 = 0; h4 < 8; ++h4) {
        float4 qv = *(const float4*)&qt[i][h4 * 4];
        acc = fmaf(qv.x, kj[h4 * 4 + 0], acc);
        acc = fmaf(qv.y, kj[h4 * 4 + 1], acc);
        acc = fmaf(qv.z, kj[h4 * 4 + 2], acc);
        acc = fmaf(qv.w, kj[h4 * 4 + 3], acc);
      }
      e[i][j] = acc;
      mloc[i] = fmaxf(mloc[i], acc);
    }
  }
  int wave = tid >> 6, lane = tid & 63;
#pragma unroll
  for (int i = 0; i < TI; ++i)
#pragma unroll
    for (int off = 32; off > 0; off >>= 1)
      mloc[i] = fmaxf(mloc[i], __shfl_xor(mloc[i], off));
  if (lane == 0) {
#pragma unroll
    for (int i = 0; i < TI; ++i) red[wave][i] = mloc[i];
  }
  __syncthreads();
  float mfin[TI];
#pragma unroll
  for (int i = 0; i < TI; ++i)
    mfin[i] = fmaxf(fmaxf(red[0][i], red[1][i]), fmaxf(red[2][i], red[3][i]));
  __syncthreads();
  float lloc[TI] = {};
#pragma unroll 1
  for (int s = 0; s < 8; ++s) {
    int j = tid + s * 256;
#pragma unroll
    for (int i = 0; i < TI; ++i) {
      float v = __expf(e[i][j] - mfin[i]);
      e[i][j] = v;
      lloc[i] += v;
    }
  }
#pragma unroll
  for (int i = 0; i < TI; ++i)
#pragma unroll
    for (int off = 32; off > 0; off >>= 1)
      lloc[i] += __shfl_xor(lloc[i], off);
  if (lane == 0) {
#pragma unroll
    for (int i = 0; i < TI; ++i) red[wave][i] = lloc[i];
  }
  __syncthreads();
  float linv[TI];
#pragma unroll
  for (int i = 0; i < TI; ++i)
    linv[i] = 1.0f / (red[0][i] + red[1][i] + red[2][i] + red[3][i]);
#pragma unroll 1
  for (int s = 0; s < 8; ++s) {
    int j = tid + s * 256;
#pragma unroll
    for (int i = 0; i < TI; ++i)
      W[((size_t)b * chunkN + iT + i) * (size_t)N_ + j] =
          __float2bfloat16(e[i][j] * linv[i]);
  }
}

extern "C" void kernel_launch(void* const* d_in, const int* in_sizes, int n_in,
                              void* d_out, int out_size, void* d_ws, size_t ws_size,
                              hipStream_t stream) {
  const float* x  = (const float*)d_in[0];
  const float* wq = (const float*)d_in[1];
  const float* bq = (const float*)d_in[2];
  const float* wk = (const float*)d_in[3];
  const float* bk = (const float*)d_in[4];
  const float* wv = (const float*)d_in[5];
  const float* bv = (const float*)d_in[6];
  float* out = (float*)d_out;

  char* ws = (char*)d_ws;
  float* q  = (float*)ws;                               // 2 MB
  float* kk = (float*)(ws + (size_t)B_ * H_ * N_ * 4);  // 2 MB
  size_t off = (size_t)2 * B_ * H_ * N_ * 4;
  __hip_bfloat16* vbf = (__hip_bfloat16*)(ws + off);    // [b][c][n] bf16, 8 MB
  off += (size_t)B_ * C_ * N_ * 2;
  __hip_bfloat16* xt = (__hip_bfloat16*)(ws + off);     // [b][n][c] bf16, 8 MB
  off += (size_t)B_ * N_ * C_ * 2;
  __hip_bfloat16* wvbf = (__hip_bfloat16*)(ws + off);   // 128 KB
  off += (size_t)C_ * C_ * 2;
  __hip_bfloat16* W = (__hip_bfloat16*)(ws + off);      // [b][chunk][N] bf16

  int chunk = N_;
  while (chunk > 128 && off + (size_t)B_ * chunk * N_ * 2 > ws_size) chunk >>= 1;

  // K1: q,k projections (fp32 VALU)
  qk_kernel<<<dim3(N_ / 64, H_ / 4, B_), 256, 0, stream>>>(x, wq, bq, wk, bk, q, kk);
  // x -> xt (bf16 transposed), wv -> bf16
  transpose_kernel<<<dim3(N_ / 64, C_ / 64, B_), 256, 0, stream>>>(x, xt);
  cvt_kernel<<<dim3((C_ * C_ + 255) / 256), 256, 0, stream>>>(wv, wvbf, C_ * C_);

  // K2: v[b][d][n] = sum_c wv[d][c] * x[b][c][n] + bv[d]   (MFMA)
  // A = wvbf [d][c], B = xt[b] [n][c], Co = vbf [b][d][n]
  mfma_gemm<0><<<dim3(C_ / TM, N_ / TN, B_), 256, 0, stream>>>(
      wvbf, xt, (void*)vbf, bv,
      /*K=*/C_, /*lda=*/C_, /*ldb=*/C_, /*ldc=*/N_,
      /*batchA=*/0, /*batchB=*/(size_t)N_ * C_, /*batchC=*/(size_t)C_ * N_, 0);

  for (int cc = 0; cc < N_ / chunk; ++cc) {
    // K3: W[b][i][j] = softmax_j( q[b,:,i] . k[b,:,j] )
    softmax_kernel<<<dim3(chunk / TI, B_), 256, 0, stream>>>(q, kk, W, cc * chunk, chunk);
    // K4: out[b][c][i] = sum_j vbf[b][c][j] * W[b][i][j] + x[b][c][i]  (MFMA)
    // A = vbf[b] [c][j], B = W[b] [i][j], Co = out [b][c][i]
    mfma_gemm<1><<<dim3(C_ / TM, chunk / TN, B_), 256, 0, stream>>>(
        vbf, W, (void*)out, x,
        /*K=*/N_, /*lda=*/N_, /*ldb=*/N_, /*ldc=*/N_,
        /*batchA=*/(size_t)C_ * N_, /*batchB=*/(size_t)chunk * N_,
        /*batchC=*/(size_t)C_ * N_, /*nBase=*/cc * chunk);
  }
}

// Round 3
// 193.642 us; speedup vs baseline: 2.2755x; 1.2670x over previous
//
#include <hip/hip_runtime.h>
#include <hip/hip_bf16.h>
#include <cstdint>
#include <cstddef>

#define B_ 8
#define C_ 256
#define N_ 2048
#define H_ 32

typedef __bf16 bf8 __attribute__((ext_vector_type(8)));
typedef float f4 __attribute__((ext_vector_type(4)));

__device__ inline void gload_lds16(const void* g, void* l) {
  __builtin_amdgcn_global_load_lds(
      (const __attribute__((address_space(1))) unsigned int*)g,
      (__attribute__((address_space(3))) unsigned int*)l, 16, 0, 0);
}

// ---- K1: q,k projections (bf16 [b][n][h]) + fused x transpose (bf16 [b][n][c])
__global__ __launch_bounds__(256) void qkt_kernel(
    const float* __restrict__ x, const float* __restrict__ wq,
    const float* __restrict__ bq, const float* __restrict__ wk,
    const float* __restrict__ bk, __hip_bfloat16* __restrict__ qb,
    __hip_bfloat16* __restrict__ kb, __hip_bfloat16* __restrict__ xt) {
  __shared__ __hip_bfloat16 t[64][258];   // row stride 129 dwords -> conflict-free col writes
  int lane = threadIdx.x & 63, wv = threadIdx.x >> 6;
  int n0 = blockIdx.x * 64;
  int n = n0 + lane;
  int b = blockIdx.y;
  int h0 = __builtin_amdgcn_readfirstlane(wv * 8);
  const float* xb = x + (size_t)b * C_ * N_ + n;
  float aq[8], ak[8];
#pragma unroll
  for (int hh = 0; hh < 8; ++hh) { aq[hh] = bq[h0 + hh]; ak[hh] = bk[h0 + hh]; }
#pragma unroll 4
  for (int c = 0; c < C_; ++c) {
    float xv = xb[(size_t)c * N_];        // coalesced; waves 1-3 hit L1
    if (wv == 0) t[lane][c] = __float2bfloat16(xv);
#pragma unroll
    for (int hh = 0; hh < 8; ++hh) {
      aq[hh] = fmaf(xv, wq[(h0 + hh) * C_ + c], aq[hh]);  // scalar (wave-uniform) loads
      ak[hh] = fmaf(xv, wk[(h0 + hh) * C_ + c], ak[hh]);
    }
  }
  bf8 qv, kv;
#pragma unroll
  for (int hh = 0; hh < 8; ++hh) { qv[hh] = (__bf16)aq[hh]; kv[hh] = (__bf16)ak[hh]; }
  *(bf8*)(qb + ((size_t)b * N_ + n) * H_ + h0) = qv;   // 16-B aligned
  *(bf8*)(kb + ((size_t)b * N_ + n) * H_ + h0) = kv;
  __syncthreads();
  // write xt[b][n0+r][c]: 64 rows x 128 dwords, globally contiguous
  uint32_t* xtw = (uint32_t*)(xt + (size_t)b * N_ * C_ + (size_t)n0 * C_);
#pragma unroll
  for (int it = 0; it < 32; ++it) {
    int idx = it * 256 + threadIdx.x;
    int r = idx >> 7, dc = idx & 127;
    xtw[idx] = *(const uint32_t*)&t[r][dc * 2];
  }
}

// ---- tiny: wv fp32 -> bf16 ----
__global__ __launch_bounds__(256) void cvt_kernel(const float* __restrict__ s,
                                                  __hip_bfloat16* __restrict__ d, int n) {
  int i = blockIdx.x * 256 + threadIdx.x;
  if (i < n) d[i] = __float2bfloat16(s[i]);
}

// ---- K2: MFMA GEMM C[m][n] = sum_k A[m][k]*B[n][k] + bias[m], bf16 out ----
#define TM 128
#define TN 128
#define TKS 32

__global__ __launch_bounds__(256) void mfma_gemm(
    const __hip_bfloat16* __restrict__ A, const __hip_bfloat16* __restrict__ Bm,
    __hip_bfloat16* __restrict__ Co, const float* __restrict__ bias,
    int K, int lda, int ldb, int ldc,
    size_t batchA, size_t batchB, size_t batchC) {
  __shared__ __attribute__((aligned(16))) __hip_bfloat16 As[TM * TKS];
  __shared__ __attribute__((aligned(16))) __hip_bfloat16 Bs[TN * TKS];
  int tid = threadIdx.x;
  int wv = tid >> 6, lane = tid & 63;
  int z = blockIdx.z;
  const __hip_bfloat16* Ab = A + batchA * z + (size_t)(blockIdx.x * TM) * lda;
  const __hip_bfloat16* Bb = Bm + batchB * z + (size_t)(blockIdx.y * TN) * ldb;
  int srow = wv * 32 + (lane >> 2);
  int skcol = (lane & 3) * 8;
  int wm = (wv & 1) * 64, wn = (wv >> 1) * 64;
  int fcol = (lane & 15), fk = (lane >> 4) * 8;
  f4 acc[4][4] = {};
  for (int k0 = 0; k0 < K; k0 += TKS) {
    __syncthreads();
    gload_lds16(Ab + (size_t)srow * lda + k0 + skcol, &As[(wv * 32) * TKS]);
    gload_lds16(Ab + (size_t)(srow + 16) * lda + k0 + skcol, &As[(wv * 32 + 16) * TKS]);
    gload_lds16(Bb + (size_t)srow * ldb + k0 + skcol, &Bs[(wv * 32) * TKS]);
    gload_lds16(Bb + (size_t)(srow + 16) * ldb + k0 + skcol, &Bs[(wv * 32 + 16) * TKS]);
    __syncthreads();
    bf8 af[4], bfr[4];
#pragma unroll
    for (int t = 0; t < 4; ++t) {
      af[t] = *(const bf8*)&As[(wm + t * 16 + fcol) * TKS + fk];
      bfr[t] = *(const bf8*)&Bs[(wn + t * 16 + fcol) * TKS + fk];
    }
#pragma unroll
    for (int ti = 0; ti < 4; ++ti)
#pragma unroll
      for (int tj = 0; tj < 4; ++tj)
        acc[ti][tj] = __builtin_amdgcn_mfma_f32_16x16x32_bf16(af[ti], bfr[tj], acc[ti][tj], 0, 0, 0);
  }
  int rq = (lane >> 4) * 4;
#pragma unroll
  for (int ti = 0; ti < 4; ++ti)
#pragma unroll
    for (int r = 0; r < 4; ++r) {
      int m = blockIdx.x * TM + wm + ti * 16 + rq + r;
#pragma unroll
      for (int tj = 0; tj < 4; ++tj) {
        int n = blockIdx.y * TN + wn + tj * 16 + fcol;
        Co[batchC * z + (size_t)m * ldc + n] = __float2bfloat16(acc[ti][tj][r] + bias[m]);
      }
    }
}

// ---- fused attention: S=qk^T (MFMA) -> exp (no max-sub) -> O=V.P^T (MFMA) ----
// wg tile: c=128, i=64. Wave w owns i-slice of 16 queries.
#define FC 128
#define FI 64
#define PSTR 40   // pS row stride in bf16 (80 B: 16-B aligned, 2-way-bank only)

__global__ __launch_bounds__(256, 2) void fused_attn(
    const __hip_bfloat16* __restrict__ qb,  // [b][n][H]
    const __hip_bfloat16* __restrict__ kb,  // [b][n][H]
    const __hip_bfloat16* __restrict__ vbf, // [b][c][n]
    const float* __restrict__ x, float* __restrict__ out) {
  __shared__ __attribute__((aligned(16))) __hip_bfloat16 vS[FC * 32];   // 8 KB
  __shared__ __attribute__((aligned(16))) __hip_bfloat16 pS[4][16 * PSTR];
  __shared__ float lS[FI];
  int tid = threadIdx.x;
  int wv = tid >> 6, lane = tid & 63;
  int b = blockIdx.z;
  int c0 = blockIdx.x * FC;
  int i0 = blockIdx.y * FI;
  int fcol = lane & 15, fk8 = (lane >> 4) * 8;

  // preload q A-frag for this wave's 16 queries (i = i0 + wv*16 + fcol)
  bf8 qf = *(const bf8*)&qb[((size_t)b * N_ + i0 + wv * 16 + fcol) * H_ + fk8];

  const __hip_bfloat16* vB = vbf + (size_t)b * C_ * N_ + (size_t)c0 * N_;
  const __hip_bfloat16* kB = kb + (size_t)b * N_ * H_;
  int srow = wv * 32 + (lane >> 2);    // v staging rows (c-local), 2 issues/wave
  int skcol = (lane & 3) * 8;

  f4 acc[8] = {};      // [c-tile 0..8) x (16c x 16i)
  float lp[4] = {};    // l partials for rows (lane>>4)*4 + r
  __hip_bfloat16* pW = &pS[wv][0];

  for (int j0 = 0; j0 < N_; j0 += 32) {
    __syncthreads();
    // stage v-tile [c=128][j=32] (HBM/L2 -> LDS, coalesced 16B/lane)
    gload_lds16(vB + (size_t)srow * N_ + j0 + skcol, &vS[(wv * 32) * 32]);
    gload_lds16(vB + (size_t)(srow + 16) * N_ + j0 + skcol, &vS[(wv * 32 + 16) * 32]);
    // S-tile: this wave's 16 i x 32 j
    bf8 kf0 = *(const bf8*)&kB[(size_t)(j0 + fcol) * H_ + fk8];
    bf8 kf1 = *(const bf8*)&kB[(size_t)(j0 + 16 + fcol) * H_ + fk8];
    f4 s0 = {}, s1 = {};
    s0 = __builtin_amdgcn_mfma_f32_16x16x32_bf16(qf, kf0, s0, 0, 0, 0);
    s1 = __builtin_amdgcn_mfma_f32_16x16x32_bf16(qf, kf1, s1, 0, 0, 0);
    // exp (no max subtraction: |S| << 88), accumulate l, write P to per-wave LDS
#pragma unroll
    for (int r = 0; r < 4; ++r) {
      int row = (lane >> 4) * 4 + r;    // i-local
      float p0 = __expf(s0[r]);
      float p1 = __expf(s1[r]);
      lp[r] += p0 + p1;
      pW[row * PSTR + fcol] = __float2bfloat16(p0);
      pW[row * PSTR + 16 + fcol] = __float2bfloat16(p1);
    }
    __syncthreads();   // drains gload (vS ready); pS is same-wave (lgkmcnt)
    // P B-frag: B[n=i-local][k=j-local]
    bf8 pf = *(const bf8*)&pW[fcol * PSTR + fk8];
    bf8 vf[8];
#pragma unroll
    for (int t = 0; t < 8; ++t)
      vf[t] = *(const bf8*)&vS[(t * 16 + fcol) * 32 + fk8];
#pragma unroll
    for (int t = 0; t < 8; ++t)
      acc[t] = __builtin_amdgcn_mfma_f32_16x16x32_bf16(vf[t], pf, acc[t], 0, 0, 0);
  }

  // finalize l: butterfly over the 16 lanes sharing (lane>>4)
#pragma unroll
  for (int r = 0; r < 4; ++r) {
    float v = lp[r];
    v += __shfl_xor(v, 1); v += __shfl_xor(v, 2);
    v += __shfl_xor(v, 4); v += __shfl_xor(v, 8);
    if ((lane & 15) == 0) lS[wv * 16 + (lane >> 4) * 4 + r] = v;
  }
  float linv = 1.0f / lS[wv * 16 + fcol];   // same-wave LDS: in-order + lgkmcnt
  int i = i0 + wv * 16 + fcol;
  int rq = (lane >> 4) * 4;
  const float* xr = x + (size_t)b * C_ * N_;
  float* outp = out + (size_t)b * C_ * N_;
#pragma unroll
  for (int t = 0; t < 8; ++t)
#pragma unroll
    for (int r = 0; r < 4; ++r) {
      int c = c0 + t * 16 + rq + r;
      size_t off = (size_t)c * N_ + i;
      outp[off] = acc[t][r] * linv + xr[off];
    }
}

extern "C" void kernel_launch(void* const* d_in, const int* in_sizes, int n_in,
                              void* d_out, int out_size, void* d_ws, size_t ws_size,
                              hipStream_t stream) {
  const float* x  = (const float*)d_in[0];
  const float* wq = (const float*)d_in[1];
  const float* bq = (const float*)d_in[2];
  const float* wk = (const float*)d_in[3];
  const float* bk = (const float*)d_in[4];
  const float* wv = (const float*)d_in[5];
  const float* bv = (const float*)d_in[6];
  float* out = (float*)d_out;

  char* ws = (char*)d_ws;
  __hip_bfloat16* qb   = (__hip_bfloat16*)ws;                        // 1 MB [b][n][H]
  __hip_bfloat16* kbuf = (__hip_bfloat16*)(ws + (1u << 20));         // 1 MB [b][n][H]
  __hip_bfloat16* vbf  = (__hip_bfloat16*)(ws + (2u << 20));         // 8 MB [b][c][n]
  __hip_bfloat16* xt   = (__hip_bfloat16*)(ws + (10u << 20));        // 8 MB [b][n][c]
  __hip_bfloat16* wvbf = (__hip_bfloat16*)(ws + (18u << 20));        // 128 KB

  // K1: q,k (bf16, [b][n][h]) + xt transpose
  qkt_kernel<<<dim3(N_ / 64, B_), 256, 0, stream>>>(x, wq, bq, wk, bk, qb, kbuf, xt);
  cvt_kernel<<<dim3((C_ * C_ + 255) / 256), 256, 0, stream>>>(wv, wvbf, C_ * C_);

  // K2: v[b][d][n] = sum_c wv[d][c]*x[b][c][n] + bv[d]  (MFMA)
  mfma_gemm<<<dim3(C_ / TM, N_ / TN, B_), 256, 0, stream>>>(
      wvbf, xt, vbf, bv,
      /*K=*/C_, /*lda=*/C_, /*ldb=*/C_, /*ldc=*/N_,
      /*batchA=*/0, /*batchB=*/(size_t)N_ * C_, /*batchC=*/(size_t)C_ * N_);

  // K3+K4 fused: out = V . softmax(QK^T)^T / l + x
  fused_attn<<<dim3(C_ / FC, N_ / FI, B_), 256, 0, stream>>>(qb, kbuf, vbf, x, out);
}

// Round 4
// 145.065 us; speedup vs baseline: 3.0375x; 1.3349x over previous
//
#include <hip/hip_runtime.h>
#include <hip/hip_bf16.h>
#include <cstdint>
#include <cstddef>

#define B_ 8
#define C_ 256
#define N_ 2048
#define H_ 32

typedef __bf16 bf8 __attribute__((ext_vector_type(8)));
typedef float f4 __attribute__((ext_vector_type(4)));

__device__ inline void gload_lds16(const void* g, void* l) {
  __builtin_amdgcn_global_load_lds(
      (const __attribute__((address_space(1))) unsigned int*)g,
      (__attribute__((address_space(3))) unsigned int*)l, 16, 0, 0);
}

// ---- transpose+cast: x[b][c][n] fp32 -> xt[b][n][c] bf16 ----
__global__ __launch_bounds__(256) void transpose_kernel(
    const float* __restrict__ x, __hip_bfloat16* __restrict__ xt) {
  __shared__ __hip_bfloat16 t[64][66];  // row 132 B = 33 dw -> conflict-free col reads
  int b = blockIdx.z;
  int n0 = blockIdx.x * 64, c0 = blockIdx.y * 64;
  const float* xb = x + (size_t)b * C_ * N_;
  __hip_bfloat16* xtb = xt + (size_t)b * N_ * C_;
  int tl = threadIdx.x & 63, tq = threadIdx.x >> 6;
#pragma unroll
  for (int p = 0; p < 16; ++p) {
    int c = tq * 16 + p;
    t[c][tl] = __float2bfloat16(xb[(size_t)(c0 + c) * N_ + n0 + tl]);
  }
  __syncthreads();
#pragma unroll
  for (int p = 0; p < 16; ++p) {
    int n = tq * 16 + p;
    xtb[(size_t)(n0 + n) * C_ + c0 + tl] = t[tl][n];
  }
}

// ---- pack wq,wk -> wqk bf16 [64][C], bq,bk -> bqk fp32 [64] ----
__global__ __launch_bounds__(256) void pack_wqk(
    const float* __restrict__ wq, const float* __restrict__ wk,
    const float* __restrict__ bq, const float* __restrict__ bk,
    __hip_bfloat16* __restrict__ wqk, float* __restrict__ bqk) {
  int idx = blockIdx.x * 256 + threadIdx.x;
  if (idx < 64 * C_) {
    int row = idx >> 8;
    float v = (row < 32) ? wq[idx] : wk[idx - 32 * C_];
    wqk[idx] = __float2bfloat16(v);
  }
  if (idx < 64) bqk[idx] = (idx < 32) ? bq[idx] : bk[idx - 32];
}

// ---- tiny: wv fp32 -> bf16 ----
__global__ __launch_bounds__(256) void cvt_kernel(const float* __restrict__ s,
                                                  __hip_bfloat16* __restrict__ d, int n) {
  int i = blockIdx.x * 256 + threadIdx.x;
  if (i < n) d[i] = __float2bfloat16(s[i]);
}

// ---- qk GEMM: qk[b][n][64] = xt[b][n][:] . wqk[h][:] + bqk[h]  (bf16 out) ----
__global__ __launch_bounds__(256) void qk_gemm(
    const __hip_bfloat16* __restrict__ xt, const __hip_bfloat16* __restrict__ wqk,
    const float* __restrict__ bqk, __hip_bfloat16* __restrict__ qk) {
  __shared__ __attribute__((aligned(16))) __hip_bfloat16 As[128 * 32];
  __shared__ __attribute__((aligned(16))) __hip_bfloat16 Bs[64 * 32];
  int tid = threadIdx.x, wv = tid >> 6, lane = tid & 63;
  int b = blockIdx.y;
  const __hip_bfloat16* Ab = xt + ((size_t)b * N_ + blockIdx.x * 128) * C_;
  int fcol = lane & 15, fk = (lane >> 4) * 8;
  int sr = lane >> 2, sc = (lane & 3) * 8;   // 16 rows x 64 B per gload
  f4 acc[2][4] = {};
  for (int k0 = 0; k0 < C_; k0 += 32) {
    __syncthreads();
    gload_lds16(Ab + (size_t)(wv * 32 + sr) * C_ + k0 + sc, &As[(wv * 32) * 32]);
    gload_lds16(Ab + (size_t)(wv * 32 + 16 + sr) * C_ + k0 + sc, &As[(wv * 32 + 16) * 32]);
    gload_lds16(wqk + (size_t)(wv * 16 + sr) * C_ + k0 + sc, &Bs[(wv * 16) * 32]);
    __syncthreads();
    bf8 af[2], bfr[4];
#pragma unroll
    for (int i = 0; i < 2; ++i) af[i] = *(const bf8*)&As[(wv * 32 + i * 16 + fcol) * 32 + fk];
#pragma unroll
    for (int j = 0; j < 4; ++j) bfr[j] = *(const bf8*)&Bs[(j * 16 + fcol) * 32 + fk];
#pragma unroll
    for (int i = 0; i < 2; ++i)
#pragma unroll
      for (int j = 0; j < 4; ++j)
        acc[i][j] = __builtin_amdgcn_mfma_f32_16x16x32_bf16(af[i], bfr[j], acc[i][j], 0, 0, 0);
  }
  int rq = (lane >> 4) * 4;
#pragma unroll
  for (int i = 0; i < 2; ++i)
#pragma unroll
    for (int r = 0; r < 4; ++r) {
      int m = blockIdx.x * 128 + wv * 32 + i * 16 + rq + r;
#pragma unroll
      for (int j = 0; j < 4; ++j) {
        int col = j * 16 + fcol;
        qk[((size_t)b * N_ + m) * 64 + col] = __float2bfloat16(acc[i][j][r] + bqk[col]);
      }
    }
}

// ---- K2: MFMA GEMM C[m][n] = sum_k A[m][k]*B[n][k] + bias[m], bf16 out ----
#define TM 128
#define TN 128

__global__ __launch_bounds__(256) void mfma_gemm(
    const __hip_bfloat16* __restrict__ A, const __hip_bfloat16* __restrict__ Bm,
    __hip_bfloat16* __restrict__ Co, const float* __restrict__ bias,
    int K, int lda, int ldb, int ldc,
    size_t batchA, size_t batchB, size_t batchC) {
  __shared__ __attribute__((aligned(16))) __hip_bfloat16 As[TM * 32];
  __shared__ __attribute__((aligned(16))) __hip_bfloat16 Bs[TN * 32];
  int tid = threadIdx.x;
  int wv = tid >> 6, lane = tid & 63;
  int z = blockIdx.z;
  const __hip_bfloat16* Ab = A + batchA * z + (size_t)(blockIdx.x * TM) * lda;
  const __hip_bfloat16* Bb = Bm + batchB * z + (size_t)(blockIdx.y * TN) * ldb;
  int srow = wv * 32 + (lane >> 2);
  int skcol = (lane & 3) * 8;
  int wm = (wv & 1) * 64, wn = (wv >> 1) * 64;
  int fcol = (lane & 15), fk = (lane >> 4) * 8;
  f4 acc[4][4] = {};
  for (int k0 = 0; k0 < K; k0 += 32) {
    __syncthreads();
    gload_lds16(Ab + (size_t)srow * lda + k0 + skcol, &As[(wv * 32) * 32]);
    gload_lds16(Ab + (size_t)(srow + 16) * lda + k0 + skcol, &As[(wv * 32 + 16) * 32]);
    gload_lds16(Bb + (size_t)srow * ldb + k0 + skcol, &Bs[(wv * 32) * 32]);
    gload_lds16(Bb + (size_t)(srow + 16) * ldb + k0 + skcol, &Bs[(wv * 32 + 16) * 32]);
    __syncthreads();
    bf8 af[4], bfr[4];
#pragma unroll
    for (int t = 0; t < 4; ++t) {
      af[t] = *(const bf8*)&As[(wm + t * 16 + fcol) * 32 + fk];
      bfr[t] = *(const bf8*)&Bs[(wn + t * 16 + fcol) * 32 + fk];
    }
#pragma unroll
    for (int ti = 0; ti < 4; ++ti)
#pragma unroll
      for (int tj = 0; tj < 4; ++tj)
        acc[ti][tj] = __builtin_amdgcn_mfma_f32_16x16x32_bf16(af[ti], bfr[tj], acc[ti][tj], 0, 0, 0);
  }
  int rq = (lane >> 4) * 4;
#pragma unroll
  for (int ti = 0; ti < 4; ++ti)
#pragma unroll
    for (int r = 0; r < 4; ++r) {
      int m = blockIdx.x * TM + wm + ti * 16 + rq + r;
#pragma unroll
      for (int tj = 0; tj < 4; ++tj) {
        int n = blockIdx.y * TN + wn + tj * 16 + fcol;
        Co[batchC * z + (size_t)m * ldc + n] = __float2bfloat16(acc[ti][tj][r] + bias[m]);
      }
    }
}

// ---- fused attention v2: dbuf vS + XOR bank swizzle + 1 barrier/iter ----
#define FC 128
#define FI 64
#define JT 64
#define PSTR 72

__global__ __launch_bounds__(256, 2) void fused_attn(
    const __hip_bfloat16* __restrict__ qk,  // [b][n][64]  (q: 0..31, k: 32..63)
    const __hip_bfloat16* __restrict__ vbf, // [b][c][n]
    const float* __restrict__ x, float* __restrict__ out) {
  __shared__ __attribute__((aligned(16))) __hip_bfloat16 vS[2][FC * JT];  // 2 x 16 KB
  __shared__ __attribute__((aligned(16))) __hip_bfloat16 pS[4][16 * PSTR];
  __shared__ float lS[FI];
  int tid = threadIdx.x;
  int wv = tid >> 6, lane = tid & 63;
  int b = blockIdx.z;
  int c0 = blockIdx.x * FC;
  int i0 = blockIdx.y * FI;
  int fcol = lane & 15, fq = lane >> 4, fk8 = fq * 8;

  const __hip_bfloat16* qkB = qk + (size_t)b * N_ * 64;
  bf8 qf = *(const bf8*)&qkB[(size_t)(i0 + wv * 16 + fcol) * 64 + fk8];

  const __hip_bfloat16* vB = vbf + ((size_t)b * C_ + c0) * N_;
  // vS staging: per gload, 8 rows x 8 chunks; global chunk = (lane&7) ^ (lane>>3)
  int grow = lane >> 3;
  int gch = ((lane & 7) ^ grow) * 8;    // element offset (x2 B = 16 B chunks)
  int xsw = (fcol & 7);                  // read-side swizzle key (m&7 == fcol&7)

  bf8 kf[4], kfn[4];
#pragma unroll
  for (int g = 0; g < 4; ++g)
    gload_lds16(vB + (size_t)(wv * 32 + g * 8 + grow) * N_ + gch, &vS[0][(wv * 32 + g * 8) * JT]);
#pragma unroll
  for (int jj = 0; jj < 4; ++jj)
    kf[jj] = *(const bf8*)&qkB[(size_t)(jj * 16 + fcol) * 64 + 32 + fk8];

  f4 acc[8] = {};
  float lp[4] = {};
  __hip_bfloat16* pW = &pS[wv][0];

  for (int t = 0; t < N_ / JT; ++t) {
    __syncthreads();                 // vS[t&1] ready; prev-iter reads done
    int buf = t & 1;
    if (t + 1 < N_ / JT) {
      int j1 = (t + 1) * JT;
#pragma unroll
      for (int g = 0; g < 4; ++g)
        gload_lds16(vB + (size_t)(wv * 32 + g * 8 + grow) * N_ + j1 + gch,
                    &vS[buf ^ 1][(wv * 32 + g * 8) * JT]);
#pragma unroll
      for (int jj = 0; jj < 4; ++jj)
        kfn[jj] = *(const bf8*)&qkB[(size_t)(j1 + jj * 16 + fcol) * 64 + 32 + fk8];
    }
    // S = q.k^T for this wave's 16 i x 64 j; exp; stash P in wave-private LDS
#pragma unroll
    for (int jj = 0; jj < 4; ++jj) {
      f4 sz = {};
      sz = __builtin_amdgcn_mfma_f32_16x16x32_bf16(qf, kf[jj], sz, 0, 0, 0);
#pragma unroll
      for (int r = 0; r < 4; ++r) {
        float p = __expf(sz[r]);     // no max-sub: |S| <~ 25 << 88
        lp[r] += p;
        pW[(fq * 4 + r) * PSTR + jj * 16 + fcol] = __float2bfloat16(p);
      }
    }
    // PV: acc[c-tile] += v-frag . P-frag  (K = 32 j per jc)
#pragma unroll
    for (int jc = 0; jc < 2; ++jc) {
      bf8 pf = *(const bf8*)&pW[fcol * PSTR + jc * 32 + fk8];
      int gsw = ((jc * 4 + fq) ^ xsw) * 8;   // swizzled chunk element offset
#pragma unroll
      for (int ct = 0; ct < 8; ++ct) {
        bf8 vf = *(const bf8*)&vS[buf][(ct * 16 + fcol) * JT + gsw];
        acc[ct] = __builtin_amdgcn_mfma_f32_16x16x32_bf16(vf, pf, acc[ct], 0, 0, 0);
      }
    }
    if (t + 1 < N_ / JT) {
#pragma unroll
      for (int jj = 0; jj < 4; ++jj) kf[jj] = kfn[jj];
    }
  }

  // finalize l over the 16 lanes sharing fq
#pragma unroll
  for (int r = 0; r < 4; ++r) {
    float v = lp[r];
    v += __shfl_xor(v, 1); v += __shfl_xor(v, 2);
    v += __shfl_xor(v, 4); v += __shfl_xor(v, 8);
    if ((lane & 15) == 0) lS[wv * 16 + fq * 4 + r] = v;
  }
  float linv = 1.0f / lS[wv * 16 + fcol];  // same-wave LDS round trip
  int i = i0 + wv * 16 + fcol;
  int rq = fq * 4;
  const float* xr = x + (size_t)b * C_ * N_;
  float* outp = out + (size_t)b * C_ * N_;
#pragma unroll
  for (int ct = 0; ct < 8; ++ct)
#pragma unroll
    for (int r = 0; r < 4; ++r) {
      int c = c0 + ct * 16 + rq + r;
      size_t off = (size_t)c * N_ + i;
      outp[off] = acc[ct][r] * linv + xr[off];
    }
}

extern "C" void kernel_launch(void* const* d_in, const int* in_sizes, int n_in,
                              void* d_out, int out_size, void* d_ws, size_t ws_size,
                              hipStream_t stream) {
  const float* x  = (const float*)d_in[0];
  const float* wq = (const float*)d_in[1];
  const float* bq = (const float*)d_in[2];
  const float* wk = (const float*)d_in[3];
  const float* bk = (const float*)d_in[4];
  const float* wv = (const float*)d_in[5];
  const float* bv = (const float*)d_in[6];
  float* out = (float*)d_out;

  char* ws = (char*)d_ws;
  __hip_bfloat16* qkb  = (__hip_bfloat16*)ws;                          // 2 MB [b][n][64]
  __hip_bfloat16* vbf  = (__hip_bfloat16*)(ws + (2u << 20));           // 8 MB [b][c][n]
  __hip_bfloat16* xt   = (__hip_bfloat16*)(ws + (10u << 20));          // 8 MB [b][n][c]
  __hip_bfloat16* wvbf = (__hip_bfloat16*)(ws + (18u << 20));          // 128 KB
  __hip_bfloat16* wqkb = (__hip_bfloat16*)(ws + (18u << 20) + (128u << 10)); // 32 KB
  float*          bqk  = (float*)(ws + (18u << 20) + (160u << 10));    // 256 B

  transpose_kernel<<<dim3(N_ / 64, C_ / 64, B_), 256, 0, stream>>>(x, xt);
  pack_wqk<<<dim3(64), 256, 0, stream>>>(wq, wk, bq, bk, wqkb, bqk);
  cvt_kernel<<<dim3((C_ * C_ + 255) / 256), 256, 0, stream>>>(wv, wvbf, C_ * C_);

  // qk[b][n][64]
  qk_gemm<<<dim3(N_ / 128, B_), 256, 0, stream>>>(xt, wqkb, bqk, qkb);

  // v[b][d][n] = wv . x + bv
  mfma_gemm<<<dim3(C_ / TM, N_ / TN, B_), 256, 0, stream>>>(
      wvbf, xt, vbf, bv,
      /*K=*/C_, /*lda=*/C_, /*ldb=*/C_, /*ldc=*/N_,
      /*batchA=*/0, /*batchB=*/(size_t)N_ * C_, /*batchC=*/(size_t)C_ * N_);

  // fused: out = V . softmax(QK^T)^T / l + x
  fused_attn<<<dim3(C_ / FC, N_ / FI, B_), 256, 0, stream>>>(qkb, vbf, x, out);
}

// Round 5
// 137.778 us; speedup vs baseline: 3.1981x; 1.0529x over previous
//
#include <hip/hip_runtime.h>
#include <hip/hip_bf16.h>
#include <cstdint>
#include <cstddef>

#define B_ 8
#define C_ 256
#define N_ 2048
#define H_ 32

typedef __bf16 bf8 __attribute__((ext_vector_type(8)));
typedef float f4 __attribute__((ext_vector_type(4)));
typedef float f16v __attribute__((ext_vector_type(16)));

__device__ inline void gload_lds16(const void* g, void* l) {
  __builtin_amdgcn_global_load_lds(
      (const __attribute__((address_space(1))) unsigned int*)g,
      (__attribute__((address_space(3))) unsigned int*)l, 16, 0, 0);
}

// ---- P1: pack weights: wpk bf16 [320][256] = {wv; wq; wk}, bpk fp32 [320] ----
__global__ __launch_bounds__(256) void pack_kernel(
    const float* __restrict__ wq, const float* __restrict__ wk,
    const float* __restrict__ wv, const float* __restrict__ bq,
    const float* __restrict__ bk, const float* __restrict__ bv,
    __hip_bfloat16* __restrict__ wpk, float* __restrict__ bpk) {
  int r = blockIdx.x, c = threadIdx.x;
  float v;
  if (r < 256)      v = wv[r * 256 + c];
  else if (r < 288) v = wq[(r - 256) * 256 + c];
  else              v = wk[(r - 288) * 256 + c];
  wpk[r * 256 + c] = __float2bfloat16(v);
  if (c == 0) bpk[r] = (r < 256) ? bv[r] : (r < 288 ? bq[r - 256] : bk[r - 288]);
}

// ---- P2: proj GEMM. C[m][n] = sum_c wpk[m][c]*x[b][c][n] + bpk[m].
// m<256 -> vbf[b][m][n] (bf16); m>=256 -> qkb[b][n][m-256] (bf16, [n][64]).
// B-fragments load DIRECTLY from fp32 x (coalesced per-c segments) + cvt:
// no transpose pass, x read exactly once.
__global__ __launch_bounds__(256) void proj_kernel(
    const float* __restrict__ x, const __hip_bfloat16* __restrict__ wpk,
    const float* __restrict__ bpk, __hip_bfloat16* __restrict__ vbf,
    __hip_bfloat16* __restrict__ qkb) {
  __shared__ __attribute__((aligned(16))) __hip_bfloat16 As[320 * 32];  // 20 KB
  int tid = threadIdx.x, wv = tid >> 6, lane = tid & 63;
  int b = blockIdx.y;
  int n0 = blockIdx.x * 32;
  int fcol = lane & 15, hi4 = lane >> 4;          // hi4: k-octet 0..3
  int grow = lane >> 2, gc = (lane & 3) * 8;      // A staging: 16 rows/gload
  const float* xb = x + (size_t)b * C_ * N_;
  f4 acc[5][2] = {};
  for (int k0 = 0; k0 < C_; k0 += 32) {
    __syncthreads();
#pragma unroll
    for (int g = 0; g < 5; ++g)
      gload_lds16(wpk + (size_t)(wv * 80 + g * 16 + grow) * 256 + k0 + gc,
                  &As[(wv * 80 + g * 16) * 32]);
    bf8 bfr[2];
#pragma unroll
    for (int j = 0; j < 2; ++j) {
      int n = n0 + j * 16 + fcol;
      float tmp[8];
#pragma unroll
      for (int e = 0; e < 8; ++e)
        tmp[e] = xb[(size_t)(k0 + hi4 * 8 + e) * N_ + n];   // 64-B segments
#pragma unroll
      for (int e = 0; e < 8; ++e) bfr[j][e] = (__bf16)tmp[e];
    }
    __syncthreads();
#pragma unroll
    for (int s = 0; s < 5; ++s) {
      bf8 af = *(const bf8*)&As[(wv * 80 + s * 16 + fcol) * 32 + hi4 * 8];
      acc[s][0] = __builtin_amdgcn_mfma_f32_16x16x32_bf16(af, bfr[0], acc[s][0], 0, 0, 0);
      acc[s][1] = __builtin_amdgcn_mfma_f32_16x16x32_bf16(af, bfr[1], acc[s][1], 0, 0, 0);
    }
  }
  int rq = hi4 * 4;
#pragma unroll
  for (int s = 0; s < 5; ++s)
#pragma unroll
    for (int r = 0; r < 4; ++r) {
      int m = wv * 80 + s * 16 + rq + r;
      float bias = bpk[m];
#pragma unroll
      for (int j = 0; j < 2; ++j) {
        int n = n0 + j * 16 + fcol;
        float val = acc[s][j][r] + bias;
        if (m < 256)
          vbf[((size_t)b * C_ + m) * N_ + n] = __float2bfloat16(val);
        else
          qkb[((size_t)b * N_ + n) * 64 + (m - 256)] = __float2bfloat16(val);
      }
    }
}

// ---- fused attention v3: 32x32x16 MFMA, 1 barrier/iter, dbuf vS+P ----
// block: c=128 x i=64. wave (iw=wv>>1, cw=wv&1): acc c-half cw (64) x i-half iw (32).
// S quadrant [iw][cw] computed once per wave (no duplication); P shared via LDS.
#define FJT 64

__global__ __launch_bounds__(256, 2) void fused_attn(
    const __hip_bfloat16* __restrict__ qk,   // [b][n][64]: q 0..31, k 32..63
    const __hip_bfloat16* __restrict__ vbf,  // [b][c][n]
    const float* __restrict__ x, float* __restrict__ out) {
  __shared__ __attribute__((aligned(16))) __hip_bfloat16 vS[2][128 * FJT];  // 32 KB
  __shared__ __attribute__((aligned(16))) __hip_bfloat16 pS[2][2][32 * 72]; // 18 KB
  __shared__ float lSp[2][2][32];
  int tid = threadIdx.x;
  int wv = tid >> 6, lane = tid & 63;
  int iw = wv >> 1, cw = wv & 1;
  int b = blockIdx.z;
  int c0 = blockIdx.x * 128;
  int i0 = blockIdx.y * 64;
  int l31 = lane & 31, hi = lane >> 5;

  const __hip_bfloat16* qkB = qk + (size_t)b * N_ * 64;
  // q A-frags: rows i = i0 + iw*32 + l31, k-octet hi*8 within each K=16 half
  bf8 qf0 = *(const bf8*)&qkB[(size_t)(i0 + iw * 32 + l31) * 64 + hi * 8];
  bf8 qf1 = *(const bf8*)&qkB[(size_t)(i0 + iw * 32 + l31) * 64 + 16 + hi * 8];

  const __hip_bfloat16* vB = vbf + ((size_t)b * C_ + c0) * N_;
  // vS staging: XOR-swizzled 16-B chunks: slot s holds global chunk s^(row&7)
  int grow = lane >> 3;
  int gch = ((lane & 7) ^ (grow & 7)) * 8;
  int kjrow = cw * 32 + l31;     // this wave's k rows (j-local half)

  bf8 kf0, kf1, kn0, kn1;
#pragma unroll
  for (int g = 0; g < 4; ++g)
    gload_lds16(vB + (size_t)(wv * 32 + g * 8 + grow) * N_ + gch,
                &vS[0][(wv * 32 + g * 8) * FJT]);
  kf0 = *(const bf8*)&qkB[(size_t)kjrow * 64 + 32 + hi * 8];
  kf1 = *(const bf8*)&qkB[(size_t)kjrow * 64 + 32 + 16 + hi * 8];

  f16v acc0 = {}, acc1 = {};
  float lp[16];
#pragma unroll
  for (int r = 0; r < 16; ++r) lp[r] = 0.f;

  for (int t = 0; t < N_ / FJT; ++t) {
    int buf = t & 1;
    // S quadrant: 32i x 32j, K=32 via two K=16 MFMAs
    f16v s = {};
    s = __builtin_amdgcn_mfma_f32_32x32x16_bf16(qf0, kf0, s, 0, 0, 0);
    s = __builtin_amdgcn_mfma_f32_32x32x16_bf16(qf1, kf1, s, 0, 0, 0);
    __hip_bfloat16* pW = &pS[buf][iw][0];
#pragma unroll
    for (int r = 0; r < 16; ++r) {
      float p = __expf(s[r]);              // no max-sub: |S| << 88
      lp[r] += p;
      int row = (r & 3) + 8 * (r >> 2) + 4 * hi;
      pW[row * 72 + cw * 32 + l31] = __float2bfloat16(p);
    }
    __syncthreads();   // drains vS[buf] gloads (issued last iter); publishes P[buf]
    if (t + 1 < N_ / FJT) {
      int j1 = (t + 1) * FJT;
#pragma unroll
      for (int g = 0; g < 4; ++g)
        gload_lds16(vB + (size_t)(wv * 32 + g * 8 + grow) * N_ + j1 + gch,
                    &vS[buf ^ 1][(wv * 32 + g * 8) * FJT]);
      kn0 = *(const bf8*)&qkB[(size_t)(j1 + kjrow) * 64 + 32 + hi * 8];
      kn1 = *(const bf8*)&qkB[(size_t)(j1 + kjrow) * 64 + 32 + 16 + hi * 8];
      // PV for this iter runs below; these drain at the NEXT barrier.
    }
    const __hip_bfloat16* pR = &pS[buf][iw][0];
    int r0 = cw * 64 + l31, r1 = r0 + 32;
    int sw = r0 & 7;                        // (r1&7)==(r0&7)
#pragma unroll
    for (int jc = 0; jc < 4; ++jc) {
      int ch = jc * 2 + hi;
      bf8 pf = *(const bf8*)&pR[l31 * 72 + jc * 16 + hi * 8];
      bf8 vf0 = *(const bf8*)&vS[buf][r0 * FJT + ((ch ^ sw) * 8)];
      bf8 vf1 = *(const bf8*)&vS[buf][r1 * FJT + ((ch ^ sw) * 8)];
      acc0 = __builtin_amdgcn_mfma_f32_32x32x16_bf16(vf0, pf, acc0, 0, 0, 0);
      acc1 = __builtin_amdgcn_mfma_f32_32x32x16_bf16(vf1, pf, acc1, 0, 0, 0);
    }
    if (t + 1 < N_ / FJT) { kf0 = kn0; kf1 = kn1; }
  }

  // l: reduce over j-lanes (bits 0..4 keep hi), publish per (iw,cw), combine
#pragma unroll
  for (int r = 0; r < 16; ++r) {
    float v = lp[r];
    v += __shfl_xor(v, 1); v += __shfl_xor(v, 2); v += __shfl_xor(v, 4);
    v += __shfl_xor(v, 8); v += __shfl_xor(v, 16);
    lp[r] = v;
  }
  if (l31 == 0) {
#pragma unroll
    for (int r = 0; r < 16; ++r)
      lSp[iw][cw][(r & 3) + 8 * (r >> 2) + 4 * hi] = lp[r];
  }
  __syncthreads();
  float linv = 1.0f / (lSp[iw][0][l31] + lSp[iw][1][l31]);
  int i = i0 + iw * 32 + l31;
  const float* xr = x + (size_t)b * C_ * N_;
  float* op = out + (size_t)b * C_ * N_;
#pragma unroll
  for (int r = 0; r < 16; ++r) {
    int row = (r & 3) + 8 * (r >> 2) + 4 * hi;
    size_t o0 = (size_t)(c0 + cw * 64 + row) * N_ + i;
    op[o0] = acc0[r] * linv + xr[o0];
    size_t o1 = o0 + (size_t)32 * N_;
    op[o1] = acc1[r] * linv + xr[o1];
  }
}

extern "C" void kernel_launch(void* const* d_in, const int* in_sizes, int n_in,
                              void* d_out, int out_size, void* d_ws, size_t ws_size,
                              hipStream_t stream) {
  const float* x  = (const float*)d_in[0];
  const float* wq = (const float*)d_in[1];
  const float* bq = (const float*)d_in[2];
  const float* wk = (const float*)d_in[3];
  const float* bk = (const float*)d_in[4];
  const float* wv = (const float*)d_in[5];
  const float* bv = (const float*)d_in[6];
  float* out = (float*)d_out;

  char* ws = (char*)d_ws;
  __hip_bfloat16* qkb = (__hip_bfloat16*)ws;                    // 2 MB [b][n][64]
  __hip_bfloat16* vbf = (__hip_bfloat16*)(ws + (2u << 20));     // 8 MB [b][c][n]
  __hip_bfloat16* wpk = (__hip_bfloat16*)(ws + (10u << 20));    // 160 KB [320][256]
  float*          bpk = (float*)(ws + (10u << 20) + (256u << 10));

  pack_kernel<<<dim3(320), 256, 0, stream>>>(wq, wk, wv, bq, bk, bv, wpk, bpk);
  proj_kernel<<<dim3(N_ / 32, B_), 256, 0, stream>>>(x, wpk, bpk, vbf, qkb);
  fused_attn<<<dim3(C_ / 128, N_ / 64, B_), 256, 0, stream>>>(qkb, vbf, x, out);
}

// Round 6
// 134.914 us; speedup vs baseline: 3.2660x; 1.0212x over previous
//
#include <hip/hip_runtime.h>
#include <hip/hip_bf16.h>
#include <cstdint>
#include <cstddef>

#define B_ 8
#define C_ 256
#define N_ 2048
#define H_ 32

typedef __bf16 bf8 __attribute__((ext_vector_type(8)));
typedef float f4 __attribute__((ext_vector_type(4)));
typedef float f16v __attribute__((ext_vector_type(16)));

__device__ inline void gload_lds16(const void* g, void* l) {
  __builtin_amdgcn_global_load_lds(
      (const __attribute__((address_space(1))) unsigned int*)g,
      (__attribute__((address_space(3))) unsigned int*)l, 16, 0, 0);
}

// ---- P1: pack weights: wpk bf16 [320][256] = {wv; wq; wk}, bpk fp32 [320] ----
__global__ __launch_bounds__(256) void pack_kernel(
    const float* __restrict__ wq, const float* __restrict__ wk,
    const float* __restrict__ wv, const float* __restrict__ bq,
    const float* __restrict__ bk, const float* __restrict__ bv,
    __hip_bfloat16* __restrict__ wpk, float* __restrict__ bpk) {
  int r = blockIdx.x, c = threadIdx.x;
  float v;
  if (r < 256)      v = wv[r * 256 + c];
  else if (r < 288) v = wq[(r - 256) * 256 + c];
  else              v = wk[(r - 288) * 256 + c];
  wpk[r * 256 + c] = __float2bfloat16(v);
  if (c == 0) bpk[r] = (r < 256) ? bv[r] : (r < 288 ? bq[r - 256] : bk[r - 288]);
}

// ---- P2: proj GEMM v2: dbuf wpk staging, reg-pipelined x frags, 1 barrier/iter.
// C[m][n] = sum_c wpk[m][c]*x[b][c][n] + bpk[m].
// m<256 -> vbf[b][m][n]; m>=256 -> qkb[b][n][m-256].
__global__ __launch_bounds__(256) void proj_kernel(
    const float* __restrict__ x, const __hip_bfloat16* __restrict__ wpk,
    const float* __restrict__ bpk, __hip_bfloat16* __restrict__ vbf,
    __hip_bfloat16* __restrict__ qkb) {
  __shared__ __attribute__((aligned(16))) __hip_bfloat16 As[2][320 * 32];  // 40 KB
  int tid = threadIdx.x, wv = tid >> 6, lane = tid & 63;
  int b = blockIdx.y;
  int n0 = blockIdx.x * 32;
  int fcol = lane & 15, hi4 = lane >> 4;          // hi4: k-octet 0..3
  int grow = lane >> 2, gc = (lane & 3) * 8;      // A staging: 16 rows/gload
  const float* xb = x + (size_t)b * C_ * N_;

  // prefetch tile 0 (wpk) + x frag 0 (regs)
#pragma unroll
  for (int g = 0; g < 5; ++g)
    gload_lds16(wpk + (size_t)(wv * 80 + g * 16 + grow) * 256 + gc,
                &As[0][(wv * 80 + g * 16) * 32]);
  float xr[2][8];
#pragma unroll
  for (int j = 0; j < 2; ++j)
#pragma unroll
    for (int e = 0; e < 8; ++e)
      xr[j][e] = xb[(size_t)(hi4 * 8 + e) * N_ + n0 + j * 16 + fcol];

  f4 acc[5][2] = {};
  for (int t = 0; t < 8; ++t) {
    int buf = t & 1;
    __syncthreads();   // drains As[buf] gloads (issued iter t-1) + xr(t) loads
    if (t < 7) {
      int k1 = (t + 1) * 32;
#pragma unroll
      for (int g = 0; g < 5; ++g)
        gload_lds16(wpk + (size_t)(wv * 80 + g * 16 + grow) * 256 + k1 + gc,
                    &As[buf ^ 1][(wv * 80 + g * 16) * 32]);
    }
    // cvt current x frag, then prefetch next into regs
    bf8 bfr[2];
#pragma unroll
    for (int j = 0; j < 2; ++j)
#pragma unroll
      for (int e = 0; e < 8; ++e) bfr[j][e] = (__bf16)xr[j][e];
    if (t < 7) {
      int k1 = (t + 1) * 32;
#pragma unroll
      for (int j = 0; j < 2; ++j)
#pragma unroll
        for (int e = 0; e < 8; ++e)
          xr[j][e] = xb[(size_t)(k1 + hi4 * 8 + e) * N_ + n0 + j * 16 + fcol];
    }
#pragma unroll
    for (int s = 0; s < 5; ++s) {
      bf8 af = *(const bf8*)&As[buf][(wv * 80 + s * 16 + fcol) * 32 + hi4 * 8];
      acc[s][0] = __builtin_amdgcn_mfma_f32_16x16x32_bf16(af, bfr[0], acc[s][0], 0, 0, 0);
      acc[s][1] = __builtin_amdgcn_mfma_f32_16x16x32_bf16(af, bfr[1], acc[s][1], 0, 0, 0);
    }
  }
  int rq = hi4 * 4;
#pragma unroll
  for (int s = 0; s < 5; ++s)
#pragma unroll
    for (int r = 0; r < 4; ++r) {
      int m = wv * 80 + s * 16 + rq + r;
      float bias = bpk[m];
#pragma unroll
      for (int j = 0; j < 2; ++j) {
        int n = n0 + j * 16 + fcol;
        float val = acc[s][j][r] + bias;
        if (m < 256)
          vbf[((size_t)b * C_ + m) * N_ + n] = __float2bfloat16(val);
        else
          qkb[((size_t)b * N_ + n) * 64 + (m - 256)] = __float2bfloat16(val);
      }
    }
}

// ---- fused attention v4: XCD-pinned b (1-D grid), 32x32x16 MFMA, dbuf ----
// block: c=128 x i=64. wave (iw=wv>>1, cw=wv&1): acc c-half cw (64) x i-half iw (32).
#define FJT 64

__global__ __launch_bounds__(256, 2) void fused_attn(
    const __hip_bfloat16* __restrict__ qk,   // [b][n][64]: q 0..31, k 32..63
    const __hip_bfloat16* __restrict__ vbf,  // [b][c][n]
    const float* __restrict__ x, float* __restrict__ out) {
  __shared__ __attribute__((aligned(16))) __hip_bfloat16 vS[2][128 * FJT];  // 32 KB
  __shared__ __attribute__((aligned(16))) __hip_bfloat16 pS[2][2][32 * 72]; // 18 KB
  __shared__ float lSp[2][2][32];
  int tid = threadIdx.x;
  int wv = tid >> 6, lane = tid & 63;
  int iw = wv >> 1, cw = wv & 1;
  // XCD-pinning decode: linear block id round-robins over 8 XCDs -> b = blk&7
  // pins all 64 blocks of batch b to XCD b; v[b]+qk[b] (1.25 MB) fits 4 MB L2.
  int blk = blockIdx.x;
  int b = blk & 7;
  int rest = blk >> 3;
  int c0 = (rest & 1) * 128;
  int i0 = (rest >> 1) * 64;
  int l31 = lane & 31, hi = lane >> 5;

  const __hip_bfloat16* qkB = qk + (size_t)b * N_ * 64;
  bf8 qf0 = *(const bf8*)&qkB[(size_t)(i0 + iw * 32 + l31) * 64 + hi * 8];
  bf8 qf1 = *(const bf8*)&qkB[(size_t)(i0 + iw * 32 + l31) * 64 + 16 + hi * 8];

  const __hip_bfloat16* vB = vbf + ((size_t)b * C_ + c0) * N_;
  // vS staging: XOR-swizzled 16-B chunks: slot s holds global chunk s^(row&7)
  int grow = lane >> 3;
  int gch = ((lane & 7) ^ (grow & 7)) * 8;
  int kjrow = cw * 32 + l31;     // this wave's k rows (j-local half)

  bf8 kf0, kf1, kn0, kn1;
#pragma unroll
  for (int g = 0; g < 4; ++g)
    gload_lds16(vB + (size_t)(wv * 32 + g * 8 + grow) * N_ + gch,
                &vS[0][(wv * 32 + g * 8) * FJT]);
  kf0 = *(const bf8*)&qkB[(size_t)kjrow * 64 + 32 + hi * 8];
  kf1 = *(const bf8*)&qkB[(size_t)kjrow * 64 + 32 + 16 + hi * 8];

  f16v acc0 = {}, acc1 = {};
  float lp[16];
#pragma unroll
  for (int r = 0; r < 16; ++r) lp[r] = 0.f;

  for (int t = 0; t < N_ / FJT; ++t) {
    int buf = t & 1;
    // S quadrant: 32i x 32j, K=32 via two K=16 MFMAs
    f16v s = {};
    s = __builtin_amdgcn_mfma_f32_32x32x16_bf16(qf0, kf0, s, 0, 0, 0);
    s = __builtin_amdgcn_mfma_f32_32x32x16_bf16(qf1, kf1, s, 0, 0, 0);
    __hip_bfloat16* pW = &pS[buf][iw][0];
#pragma unroll
    for (int r = 0; r < 16; ++r) {
      float p = __expf(s[r]);              // no max-sub: |S| << 88
      lp[r] += p;
      int row = (r & 3) + 8 * (r >> 2) + 4 * hi;
      pW[row * 72 + cw * 32 + l31] = __float2bfloat16(p);
    }
    __syncthreads();   // drains vS[buf] gloads (issued last iter); publishes P[buf]
    if (t + 1 < N_ / FJT) {
      int j1 = (t + 1) * FJT;
#pragma unroll
      for (int g = 0; g < 4; ++g)
        gload_lds16(vB + (size_t)(wv * 32 + g * 8 + grow) * N_ + j1 + gch,
                    &vS[buf ^ 1][(wv * 32 + g * 8) * FJT]);
      kn0 = *(const bf8*)&qkB[(size_t)(j1 + kjrow) * 64 + 32 + hi * 8];
      kn1 = *(const bf8*)&qkB[(size_t)(j1 + kjrow) * 64 + 32 + 16 + hi * 8];
    }
    const __hip_bfloat16* pR = &pS[buf][iw][0];
    int r0 = cw * 64 + l31, r1 = r0 + 32;
    int sw = r0 & 7;
#pragma unroll
    for (int jc = 0; jc < 4; ++jc) {
      int ch = jc * 2 + hi;
      bf8 pf = *(const bf8*)&pR[l31 * 72 + jc * 16 + hi * 8];
      bf8 vf0 = *(const bf8*)&vS[buf][r0 * FJT + ((ch ^ sw) * 8)];
      bf8 vf1 = *(const bf8*)&vS[buf][r1 * FJT + ((ch ^ sw) * 8)];
      acc0 = __builtin_amdgcn_mfma_f32_32x32x16_bf16(vf0, pf, acc0, 0, 0, 0);
      acc1 = __builtin_amdgcn_mfma_f32_32x32x16_bf16(vf1, pf, acc1, 0, 0, 0);
    }
    if (t + 1 < N_ / FJT) { kf0 = kn0; kf1 = kn1; }
  }

  // l: reduce over j-lanes, publish per (iw,cw), combine
#pragma unroll
  for (int r = 0; r < 16; ++r) {
    float v = lp[r];
    v += __shfl_xor(v, 1); v += __shfl_xor(v, 2); v += __shfl_xor(v, 4);
    v += __shfl_xor(v, 8); v += __shfl_xor(v, 16);
    lp[r] = v;
  }
  if (l31 == 0) {
#pragma unroll
    for (int r = 0; r < 16; ++r)
      lSp[iw][cw][(r & 3) + 8 * (r >> 2) + 4 * hi] = lp[r];
  }
  __syncthreads();
  float linv = 1.0f / (lSp[iw][0][l31] + lSp[iw][1][l31]);
  int i = i0 + iw * 32 + l31;
  const float* xr = x + (size_t)b * C_ * N_;
  float* op = out + (size_t)b * C_ * N_;
#pragma unroll
  for (int r = 0; r < 16; ++r) {
    int row = (r & 3) + 8 * (r >> 2) + 4 * hi;
    size_t o0 = (size_t)(c0 + cw * 64 + row) * N_ + i;
    op[o0] = acc0[r] * linv + xr[o0];
    size_t o1 = o0 + (size_t)32 * N_;
    op[o1] = acc1[r] * linv + xr[o1];
  }
}

extern "C" void kernel_launch(void* const* d_in, const int* in_sizes, int n_in,
                              void* d_out, int out_size, void* d_ws, size_t ws_size,
                              hipStream_t stream) {
  const float* x  = (const float*)d_in[0];
  const float* wq = (const float*)d_in[1];
  const float* bq = (const float*)d_in[2];
  const float* wk = (const float*)d_in[3];
  const float* bk = (const float*)d_in[4];
  const float* wv = (const float*)d_in[5];
  const float* bv = (const float*)d_in[6];
  float* out = (float*)d_out;

  char* ws = (char*)d_ws;
  __hip_bfloat16* qkb = (__hip_bfloat16*)ws;                    // 2 MB [b][n][64]
  __hip_bfloat16* vbf = (__hip_bfloat16*)(ws + (2u << 20));     // 8 MB [b][c][n]
  __hip_bfloat16* wpk = (__hip_bfloat16*)(ws + (10u << 20));    // 160 KB [320][256]
  float*          bpk = (float*)(ws + (10u << 20) + (256u << 10));

  pack_kernel<<<dim3(320), 256, 0, stream>>>(wq, wk, wv, bq, bk, bv, wpk, bpk);
  proj_kernel<<<dim3(N_ / 32, B_), 256, 0, stream>>>(x, wpk, bpk, vbf, qkb);
  fused_attn<<<dim3(512), 256, 0, stream>>>(qkb, vbf, x, out);
}